// Round 5
// baseline (604.966 us; speedup 1.0000x reference)
//
#include <hip/hip_runtime.h>

static constexpr int NN = 50000;   // nodes
static constexpr int NE = 800000;  // edges
static constexpr int D0 = 128;     // in dim
static constexpr int D1 = 256;     // hidden
static constexpr int D2 = 5;       // out

// bucketed edge sort: BSZ pow2 so bucket = dst>>8
static constexpr int BSZ   = 256;                  // nodes per bucket
static constexpr int NBUK  = (NN + BSZ - 1) / BSZ; // 196
static constexpr int CAP   = 4800;   // slab cap (mean 4081, +11 sigma)
static constexpr int CB    = 400;    // chunk blocks in pass A
static constexpr int CHUNK = 2000;   // edges per chunk (CB*CHUNK == NE)

// prepA grid partition: bucketA FIRST (heavy blocks dispatch early)
static constexpr int XB = (NN * 32 + 255) / 256;   // 6250 cvtx blocks
static constexpr int WB = (D1 * 64) / 256;         // 64 cvtw blocks
static constexpr int PB = 4;                       // w2b convert blocks

// fused agg+gemm kernel partition
static constexpr int AGB = NN / 4;                 // 12500 producer blocks
static constexpr int NT  = (NN + 127) / 128;       // 391 row tiles
static constexpr int GMB = 2 * NT;                 // 782 consumer blocks

using short8  = __attribute__((ext_vector_type(8))) short;
using floatx4 = __attribute__((ext_vector_type(4))) float;

__device__ __forceinline__ unsigned short f2b(float f) {
  union { float f; unsigned u; } v; v.f = f;
  unsigned r = v.u + 0x7fffu + ((v.u >> 16) & 1u);  // RNE
  return (unsigned short)(r >> 16);
}
__device__ __forceinline__ float b2f(unsigned short s) {
  union { unsigned u; float f; } v; v.u = ((unsigned)s) << 16;
  return v.f;
}

// ---------------- fused prep: bucketA (first) | cvtx | cvtw1 | cvtw2
__global__ __launch_bounds__(256) void k_prepA(
    const float* __restrict__ x, unsigned short* __restrict__ ab,
    const float* __restrict__ W1l, const float* __restrict__ W1r,
    unsigned short* __restrict__ wb, const float* __restrict__ W2l,
    const float* __restrict__ W2r, unsigned short* __restrict__ w2b,
    const int* __restrict__ src, const int* __restrict__ dst,
    int* __restrict__ gcur, uint2* __restrict__ slab) {
  __shared__ int hist[256], bstart[256], gbase[256], hcur[256], sscan[256];
  __shared__ uint2 pairs[CHUNK];
  const int b = blockIdx.x, t = threadIdx.x;
  if (b < CB) {  // ---- bucketA: chunk -> LDS bucket-sort -> contiguous slab
    const int e0 = b * CHUNK;
    hist[t] = 0;
    __syncthreads();
    for (int j = t; j < CHUNK; j += 256)
      atomicAdd(&hist[dst[e0 + j] >> 8], 1);
    __syncthreads();
    sscan[t] = hist[t];
    __syncthreads();
    for (int dd = 1; dd < 256; dd <<= 1) {
      int u = (t >= dd) ? sscan[t - dd] : 0;
      __syncthreads();
      sscan[t] += u;
      __syncthreads();
    }
    bstart[t] = sscan[t] - hist[t];
    gbase[t] = (t < NBUK && hist[t] > 0) ? atomicAdd(&gcur[t], hist[t]) : 0;
    hcur[t] = 0;
    __syncthreads();
    for (int j = t; j < CHUNK; j += 256) {
      const int s = src[e0 + j], d = dst[e0 + j];
      const int bk = d >> 8;
      const int pos = bstart[bk] + atomicAdd(&hcur[bk], 1);
      pairs[pos] = make_uint2((unsigned)s, (unsigned)d);
    }
    __syncthreads();
    for (int j = t; j < CHUNK; j += 256) {
      const uint2 pr = pairs[j];
      const int bk = (int)pr.y >> 8;
      slab[(size_t)bk * CAP + gbase[bk] + (j - bstart[bk])] = pr;
    }
    return;
  }
  if (b < CB + XB) {  // x -> bf16 into ab cols 128..255
    int idx = (b - CB) * 256 + t;
    if (idx < NN * 32) {
      int node = idx >> 5, cg = idx & 31;
      float4 v = *(const float4*)(x + (size_t)node * D0 + cg * 4);
      ushort4 o;
      o.x = f2b(v.x); o.y = f2b(v.y); o.z = f2b(v.z); o.w = f2b(v.w);
      *(ushort4*)(ab + (size_t)node * 256 + 128 + cg * 4) = o;
    }
    return;
  }
  if (b < CB + XB + WB) {  // [W1l|W1r] -> bf16 wb[col][256]
    int idx = (b - CB - XB) * 256 + t;
    int c = idx >> 6, k = (idx & 63) * 4;
    const float* srcp = (k < 128) ? (W1l + (size_t)c * 128 + k)
                                  : (W1r + (size_t)c * 128 + (k - 128));
    float4 v = *(const float4*)srcp;
    ushort4 o;
    o.x = f2b(v.x); o.y = f2b(v.y); o.z = f2b(v.z); o.w = f2b(v.w);
    *(ushort4*)(wb + (size_t)c * 256 + k) = o;
    return;
  }
  {  // W2l/W2r -> bf16 w2b[16][256], rows 10..15 = 0
    int idx = (b - CB - XB - WB) * 256 + t;  // [0,1024)
    int n = idx >> 6, k = (idx & 63) * 4;
    float4 v = {0.f, 0.f, 0.f, 0.f};
    if (n < 5) v = *(const float4*)(W2l + (size_t)n * D1 + k);
    else if (n < 10) v = *(const float4*)(W2r + (size_t)(n - 5) * D1 + k);
    ushort4 o;
    o.x = f2b(v.x); o.y = f2b(v.y); o.z = f2b(v.z); o.w = f2b(v.w);
    *(ushort4*)(w2b + (size_t)n * 256 + k) = o;
  }
}

// ------------------- pass BC: per-bucket CSR + LDS-staged coalesced scatter
__global__ __launch_bounds__(256) void k_bucketBC(
    const uint2* __restrict__ slab, const int* __restrict__ gcur,
    int* __restrict__ cur, float* __restrict__ inv,
    int* __restrict__ esort) {
  __shared__ int cnt[BSZ], s[BSZ], lcur[BSZ], g[256];
  __shared__ int sorted[CAP];  // 19.2 KB: LDS-staged sorted bucket
  const int b = blockIdx.x, t = threadIdx.x;
  const int n0 = b << 8;
  cnt[t] = 0;
  g[t] = (t < NBUK) ? gcur[t] : 0;
  __syncthreads();
  for (int dd = 1; dd < 256; dd <<= 1) {
    int u = (t >= dd) ? g[t - dd] : 0;
    __syncthreads();
    g[t] += u;
    __syncthreads();
  }
  const int bbase = (b == 0) ? 0 : g[b - 1];
  const int cntE = gcur[b];
  const uint2* sp = slab + (size_t)b * CAP;
  for (int j = t; j < cntE; j += 256)
    atomicAdd(&cnt[(int)sp[j].y - n0], 1);
  __syncthreads();
  s[t] = cnt[t];
  __syncthreads();
  for (int dd = 1; dd < BSZ; dd <<= 1) {
    int u = (t >= dd) ? s[t - dd] : 0;
    __syncthreads();
    s[t] += u;
    __syncthreads();
  }
  const int start = bbase + (s[t] - cnt[t]);
  const int node = n0 + t;
  if (node < NN) {
    cur[node] = start;
    inv[node] = 1.0f / (float)max(cnt[t], 1);
  }
  lcur[t] = s[t] - cnt[t];  // LOCAL offset within bucket
  if (b == NBUK - 1 && t == 0) cur[NN] = NE;
  __syncthreads();
  for (int j = t; j < cntE; j += 256) {
    const uint2 pr = sp[j];
    const int p = atomicAdd(&lcur[(int)pr.y - n0], 1);
    sorted[p] = (int)pr.x;  // random LDS write (cheap)
  }
  __syncthreads();
  for (int j = t; j < cntE; j += 256)  // coalesced global stream-out
    esort[bbase + j] = sorted[j];
}

// ===== fused agg + GEMM1 via cross-block producer/consumer tile flags =======
// Producers (blocks 0..AGB-1): EXACT round-3 k_agg1 (4 waves = 4 nodes, no
//   LDS on its path) -> full TLP for the request-bound gather (r4 lesson).
//   After mean stores: __syncthreads (drains vmcnt) + threadfence (agent
//   release: buffer_wbl2 flushes XCD-local dirty lines) + relaxed agent
//   fetch_add on done[tile].
// Consumers (blocks AGB..AGB+GMB-1): EXACT round-3 k_gemm1f tile (t,g).
//   Thread 0 polls done[t] with RELAXED agent loads (sc1 -> LLC, no inv
//   storm), then all threads threadfence (acquire: buffer_inv) so mean rows
//   are re-fetched past the stale per-XCD L2.
// Deadlock-free: producers first in dispatch order; consumers LDS-capped at
//   4 blocks/CU (16 of 32 wave slots) so producers always have wave slots.
__global__ __launch_bounds__(256) void k_aggemm2(
    unsigned short* __restrict__ ab, const unsigned short* __restrict__ wb,
    const unsigned short* __restrict__ w2b, const float* __restrict__ b1l,
    const int* __restrict__ esort, const int* __restrict__ cur,
    const float* __restrict__ inv, float* __restrict__ tt,
    float* __restrict__ rp, int* __restrict__ done) {
  __shared__ short sAB[2 * 128 * 72];  // consumer path only (36.9 KB)
  const int blk = blockIdx.x;
  const int tid = threadIdx.x;

  if (blk < AGB) {  // ---------------- producer: aggregate 4 nodes
    const int i = blk * 4 + (tid >> 6);
    const int lane = tid & 63;
    int e = cur[i];
    const int end = cur[i + 1];
    float a0 = 0.f, b0 = 0.f, a1 = 0.f, b1 = 0.f;
    float a2 = 0.f, b2 = 0.f, a3 = 0.f, b3 = 0.f;
    const unsigned short* xb = ab + 128 + lane * 2;
    while (e < end && (e & 3)) {
      const unsigned v = *(const unsigned*)(xb + (size_t)esort[e] * 256);
      a0 += b2f((unsigned short)v); b0 += b2f((unsigned short)(v >> 16));
      ++e;
    }
    for (; e + 7 < end; e += 8) {
      const int4 s0 = *(const int4*)(esort + e);
      const int4 s1 = *(const int4*)(esort + e + 4);
      const unsigned v0 = *(const unsigned*)(xb + (size_t)s0.x * 256);
      const unsigned v1 = *(const unsigned*)(xb + (size_t)s0.y * 256);
      const unsigned v2 = *(const unsigned*)(xb + (size_t)s0.z * 256);
      const unsigned v3 = *(const unsigned*)(xb + (size_t)s0.w * 256);
      const unsigned v4 = *(const unsigned*)(xb + (size_t)s1.x * 256);
      const unsigned v5 = *(const unsigned*)(xb + (size_t)s1.y * 256);
      const unsigned v6 = *(const unsigned*)(xb + (size_t)s1.z * 256);
      const unsigned v7 = *(const unsigned*)(xb + (size_t)s1.w * 256);
      a0 += b2f((unsigned short)v0); b0 += b2f((unsigned short)(v0 >> 16));
      a1 += b2f((unsigned short)v1); b1 += b2f((unsigned short)(v1 >> 16));
      a2 += b2f((unsigned short)v2); b2 += b2f((unsigned short)(v2 >> 16));
      a3 += b2f((unsigned short)v3); b3 += b2f((unsigned short)(v3 >> 16));
      a0 += b2f((unsigned short)v4); b0 += b2f((unsigned short)(v4 >> 16));
      a1 += b2f((unsigned short)v5); b1 += b2f((unsigned short)(v5 >> 16));
      a2 += b2f((unsigned short)v6); b2 += b2f((unsigned short)(v6 >> 16));
      a3 += b2f((unsigned short)v7); b3 += b2f((unsigned short)(v7 >> 16));
    }
    if (e + 3 < end) {
      const int4 s0 = *(const int4*)(esort + e);
      const unsigned v0 = *(const unsigned*)(xb + (size_t)s0.x * 256);
      const unsigned v1 = *(const unsigned*)(xb + (size_t)s0.y * 256);
      const unsigned v2 = *(const unsigned*)(xb + (size_t)s0.z * 256);
      const unsigned v3 = *(const unsigned*)(xb + (size_t)s0.w * 256);
      a0 += b2f((unsigned short)v0); b0 += b2f((unsigned short)(v0 >> 16));
      a1 += b2f((unsigned short)v1); b1 += b2f((unsigned short)(v1 >> 16));
      a2 += b2f((unsigned short)v2); b2 += b2f((unsigned short)(v2 >> 16));
      a3 += b2f((unsigned short)v3); b3 += b2f((unsigned short)(v3 >> 16));
      e += 4;
    }
    for (; e < end; ++e) {
      const unsigned v = *(const unsigned*)(xb + (size_t)esort[e] * 256);
      a0 += b2f((unsigned short)v); b0 += b2f((unsigned short)(v >> 16));
    }
    const float sc = inv[i];
    const float sa = (a0 + a1) + (a2 + a3);
    const float sb = (b0 + b1) + (b2 + b3);
    const unsigned o =
        ((unsigned)f2b(sb * sc) << 16) | (unsigned)f2b(sa * sc);
    *(unsigned*)(ab + (size_t)i * 256 + lane * 2) = o;
    __syncthreads();  // all 4 waves' stores drained (vmcnt) before fence
    if (tid == 0) {
      __threadfence();  // agent release: writeback XCD-local dirty lines
      __hip_atomic_fetch_add(done + (blk >> 5), 1, __ATOMIC_RELAXED,
                             __HIP_MEMORY_SCOPE_AGENT);
    }
    return;
  }

  // ---------------- consumer: GEMM tile (t, col-half g) + layer-2 linear
  const int cid = blk - AGB;
  const int t = cid >> 1;
  const int g = cid & 1;
  const int row0 = t * 128;
  const int col0 = g * 128;
  const int expected = min(32, (NN - row0 + 3) >> 2);

  if (tid == 0) {
    while (__hip_atomic_load(done + t, __ATOMIC_RELAXED,
                             __HIP_MEMORY_SCOPE_AGENT) < expected)
      __builtin_amdgcn_s_sleep(2);
  }
  __syncthreads();
  __threadfence();  // agent acquire: invalidate stale local L1/L2 lines

  short* sA = sAB;
  short* sB = sAB + 128 * 72;
  const int wave = tid >> 6, lane = tid & 63;
  const int quad = lane >> 4, m16 = lane & 15;
  const int wm = wave & 1, wn = wave >> 1;
  const int lr = tid >> 2;
  const int lk = (tid & 3) * 8;

  floatx4 acc[4][4];
#pragma unroll
  for (int a = 0; a < 4; ++a)
#pragma unroll
    for (int b = 0; b < 4; ++b) acc[a][b] = {0.f, 0.f, 0.f, 0.f};

  const int gr0 = row0 + lr, gr1 = row0 + lr + 64;
  const bool ok0 = gr0 < NN, ok1 = gr1 < NN;
  const unsigned short* aptr0 = ab + (size_t)gr0 * 256 + lk;
  const unsigned short* aptr1 = ab + (size_t)gr1 * 256 + lk;
  const unsigned short* bptr0 = wb + (size_t)(col0 + lr) * 256 + lk;
  const unsigned short* bptr1 = wb + (size_t)(col0 + lr + 64) * 256 + lk;
  short* sA0 = &sA[lr * 72 + lk];
  short* sA1 = &sA[(lr + 64) * 72 + lk];
  short* sB0 = &sB[lr * 72 + lk];
  short* sB1 = &sB[(lr + 64) * 72 + lk];
  const uint4 zz = make_uint4(0, 0, 0, 0);

  uint4 a00 = ok0 ? *(const uint4*)(aptr0) : zz;
  uint4 a01 = ok0 ? *(const uint4*)(aptr0 + 32) : zz;
  uint4 a10 = ok1 ? *(const uint4*)(aptr1) : zz;
  uint4 a11 = ok1 ? *(const uint4*)(aptr1 + 32) : zz;
  uint4 b00 = *(const uint4*)(bptr0);
  uint4 b01 = *(const uint4*)(bptr0 + 32);
  uint4 b10 = *(const uint4*)(bptr1);
  uint4 b11 = *(const uint4*)(bptr1 + 32);

  for (int kk = 0; kk < 256; kk += 64) {
    __syncthreads();
    *(uint4*)sA0 = a00;
    *(uint4*)(sA0 + 32) = a01;
    *(uint4*)sA1 = a10;
    *(uint4*)(sA1 + 32) = a11;
    *(uint4*)sB0 = b00;
    *(uint4*)(sB0 + 32) = b01;
    *(uint4*)sB1 = b10;
    *(uint4*)(sB1 + 32) = b11;
    __syncthreads();
    if (kk < 192) {
      const int kn = kk + 64;
      a00 = ok0 ? *(const uint4*)(aptr0 + kn) : zz;
      a01 = ok0 ? *(const uint4*)(aptr0 + kn + 32) : zz;
      a10 = ok1 ? *(const uint4*)(aptr1 + kn) : zz;
      a11 = ok1 ? *(const uint4*)(aptr1 + kn + 32) : zz;
      b00 = *(const uint4*)(bptr0 + kn);
      b01 = *(const uint4*)(bptr0 + kn + 32);
      b10 = *(const uint4*)(bptr1 + kn);
      b11 = *(const uint4*)(bptr1 + kn + 32);
    }
#pragma unroll
    for (int ko = 0; ko < 64; ko += 32) {
      short8 af[4], bf[4];
#pragma unroll
      for (int mt = 0; mt < 4; ++mt)
        af[mt] =
            *(const short8*)&sA[(wm * 64 + mt * 16 + m16) * 72 + ko + quad * 8];
#pragma unroll
      for (int nt = 0; nt < 4; ++nt)
        bf[nt] =
            *(const short8*)&sB[(wn * 64 + nt * 16 + m16) * 72 + ko + quad * 8];
#pragma unroll
      for (int mt = 0; mt < 4; ++mt)
#pragma unroll
        for (int nt = 0; nt < 4; ++nt)
          acc[mt][nt] = __builtin_amdgcn_mfma_f32_16x16x32_bf16(
              af[mt], bf[nt], acc[mt][nt], 0, 0, 0);
    }
  }

  __syncthreads();
  short* sH = sAB;  // [128][136]
#pragma unroll
  for (int nt = 0; nt < 4; ++nt) {
    const int cl = wn * 64 + nt * 16 + m16;
    const float bias = b1l[col0 + cl];
#pragma unroll
    for (int mt = 0; mt < 4; ++mt)
#pragma unroll
      for (int rg = 0; rg < 4; ++rg) {
        const int rl = wm * 64 + mt * 16 + quad * 4 + rg;
        sH[rl * 136 + cl] = (short)f2b(fmaxf(acc[mt][nt][rg] + bias, 0.f));
      }
  }
  __syncthreads();
  floatx4 c2[2] = {{0.f, 0.f, 0.f, 0.f}, {0.f, 0.f, 0.f, 0.f}};
#pragma unroll
  for (int kb = 0; kb < 4; ++kb) {
    const short8 bf2 =
        *(const short8*)&w2b[m16 * 256 + col0 + kb * 32 + quad * 8];
#pragma unroll
    for (int i = 0; i < 2; ++i) {
      const int mrow = (wave * 2 + i) * 16 + m16;
      const short8 af2 = *(const short8*)&sH[mrow * 136 + kb * 32 + quad * 8];
      c2[i] = __builtin_amdgcn_mfma_f32_16x16x32_bf16(af2, bf2, c2[i], 0, 0, 0);
    }
  }
#pragma unroll
  for (int i = 0; i < 2; ++i) {
    const int rbase = row0 + (wave * 2 + i) * 16 + quad * 4;
#pragma unroll
    for (int rg = 0; rg < 4; ++rg) {
      const int row = rbase + rg;
      if (row < NN) {
        if (m16 < 5)
          tt[(size_t)row * 16 + g * 8 + m16] = c2[i][rg];
        else if (m16 < 10)
          rp[(size_t)g * ((size_t)NN * 8) + (size_t)row * 8 + (m16 - 5)] =
              c2[i][rg];
      }
    }
  }
}

// ---------------- layer-2 aggregate: 16 lanes COOPERATE on one edge row.
// lane = dim; per edge one 64B contiguous segment. Reduce = single shfl_xor(8).
__global__ __launch_bounds__(256) void k_layer2(
    const float* __restrict__ tt, const float* __restrict__ rp,
    const int* __restrict__ esort, const int* __restrict__ cur,
    const float* __restrict__ inv, const float* __restrict__ b2l,
    float* __restrict__ out) {
  const int node = blockIdx.x * 16 + (threadIdx.x >> 4);
  const int l = threadIdx.x & 15;
  if (node >= NN) return;
  const int beg = cur[node], end = cur[node + 1];
  float s = 0.f, u = 0.f;
  int e = beg;
  for (; e + 3 < end; e += 4) {  // 4-deep ILP
    const int4 r4 = *(const int4*)(esort + e);
    const float t0 = tt[(size_t)r4.x * 16 + l];
    const float t1 = tt[(size_t)r4.y * 16 + l];
    const float t2 = tt[(size_t)r4.z * 16 + l];
    const float t3 = tt[(size_t)r4.w * 16 + l];
    s += t0 + t2;
    u += t1 + t3;
  }
  for (; e < end; ++e) s += tt[(size_t)esort[e] * 16 + l];
  s += u;
  s += __shfl_xor(s, 8, 64);  // combine K-half at pos l and l+8
  if (l < 5) {
    const float r = rp[(size_t)node * 8 + l] +
                    rp[(size_t)NN * 8 + (size_t)node * 8 + l];
    out[(size_t)node * D2 + l] = fmaxf(s * inv[node] + b2l[l] + r, 0.f);
  }
}

extern "C" void kernel_launch(void* const* d_in, const int* in_sizes, int n_in,
                              void* d_out, int out_size, void* d_ws,
                              size_t ws_size, hipStream_t stream) {
  const float* x   = (const float*)d_in[0];
  const int*   ei  = (const int*)d_in[1];
  const int*   src = ei;
  const int*   dst = ei + NE;
  const float* W1l = (const float*)d_in[2];
  const float* b1l = (const float*)d_in[3];
  const float* W1r = (const float*)d_in[4];
  const float* W2l = (const float*)d_in[5];
  const float* b2l = (const float*)d_in[6];
  const float* W2r = (const float*)d_in[7];
  float* out = (float*)d_out;

  // workspace layout: big aligned arrays first (16B-aligned offsets)
  unsigned short* ab  = (unsigned short*)d_ws;          // NN*256 bf16
  unsigned short* wb  = ab + (size_t)NN * 256;          // 256*256 bf16
  unsigned short* w2b = wb + 256 * 256;                 // 16*256 bf16
  float* tt   = (float*)(w2b + 16 * 256);               // NN*16 (t interleaved)
  float* rp   = tt + (size_t)NN * 16;                   // 2 * NN*8 (r partials)
  uint2* slab = (uint2*)(rp + (size_t)NN * 16);         // NBUK*CAP pairs
  int*   gcur = (int*)(slab + (size_t)NBUK * CAP);      // 256 ints
  int*   done = gcur + 256;                             // NT tile flags (+pad)
  int*   esort = gcur + 768;                            // NE (16B aligned)
  int*   cur  = esort + NE;                             // NN+1 (+3 pad)
  float* inv  = (float*)(cur + NN + 4);                 // NN

  hipMemsetAsync(gcur, 0, 768 * sizeof(int), stream);  // gcur + done flags

  k_prepA<<<CB + XB + WB + PB, 256, 0, stream>>>(x, ab, W1l, W1r, wb, W2l, W2r,
                                                 w2b, src, dst, gcur, slab);
  k_bucketBC<<<NBUK, 256, 0, stream>>>(slab, gcur, cur, inv, esort);
  k_aggemm2<<<AGB + GMB, 256, 0, stream>>>(ab, wb, w2b, b1l, esort, cur, inv,
                                           tt, rp, done);
  k_layer2<<<(NN + 15) / 16, 256, 0, stream>>>(tt, rp, esort, cur, inv, b2l,
                                               out);
}

// Round 6
// 176.547 us; speedup vs baseline: 3.4267x; 3.4267x over previous
//
#include <hip/hip_runtime.h>

static constexpr int NN = 50000;   // nodes
static constexpr int NE = 800000;  // edges
static constexpr int D0 = 128;     // in dim
static constexpr int D1 = 256;     // hidden
static constexpr int D2 = 5;       // out

// bucketed edge sort: BSZ pow2 so bucket = dst>>8
static constexpr int BSZ   = 256;                  // nodes per bucket
static constexpr int NBUK  = (NN + BSZ - 1) / BSZ; // 196
static constexpr int CAP   = 4800;   // slab cap (mean 4081, +11 sigma)
static constexpr int CB    = 256;    // chunk blocks: exactly 1 per CU (no tail)
static constexpr int CHUNK = 3125;   // edges per chunk (CB*CHUNK == NE)

// prepA grid partition: bucketA FIRST (heavy blocks dispatch early)
static constexpr int XB = (NN * 32 + 255) / 256;   // 6250 cvtx blocks
static constexpr int WB = (D1 * 64) / 256;         // 64 cvtw blocks
static constexpr int PB = 4;                       // w2b convert blocks

using short8  = __attribute__((ext_vector_type(8))) short;
using floatx4 = __attribute__((ext_vector_type(4))) float;

__device__ __forceinline__ unsigned short f2b(float f) {
  union { float f; unsigned u; } v; v.f = f;
  unsigned r = v.u + 0x7fffu + ((v.u >> 16) & 1u);  // RNE
  return (unsigned short)(r >> 16);
}
__device__ __forceinline__ float b2f(unsigned short s) {
  union { unsigned u; float f; } v; v.u = ((unsigned)s) << 16;
  return v.f;
}

// ---------------- fused prep: bucketA (first) | cvtx | cvtw1 | cvtw2
__global__ __launch_bounds__(256) void k_prepA(
    const float* __restrict__ x, unsigned short* __restrict__ ab,
    const float* __restrict__ W1l, const float* __restrict__ W1r,
    unsigned short* __restrict__ wb, const float* __restrict__ W2l,
    const float* __restrict__ W2r, unsigned short* __restrict__ w2b,
    const int* __restrict__ src, const int* __restrict__ dst,
    int* __restrict__ gcur, uint2* __restrict__ slab) {
  __shared__ int hist[256], bstart[256], gbase[256], hcur[256], sscan[256];
  __shared__ uint2 pairs[CHUNK];  // 25 KB
  const int b = blockIdx.x, t = threadIdx.x;
  if (b < CB) {  // ---- bucketA: chunk -> LDS bucket-sort -> contiguous slab
    const int e0 = b * CHUNK;
    hist[t] = 0;
    __syncthreads();
    for (int j = t; j < CHUNK; j += 256)
      atomicAdd(&hist[dst[e0 + j] >> 8], 1);
    __syncthreads();
    sscan[t] = hist[t];
    __syncthreads();
    for (int dd = 1; dd < 256; dd <<= 1) {
      int u = (t >= dd) ? sscan[t - dd] : 0;
      __syncthreads();
      sscan[t] += u;
      __syncthreads();
    }
    bstart[t] = sscan[t] - hist[t];
    gbase[t] = (t < NBUK && hist[t] > 0) ? atomicAdd(&gcur[t], hist[t]) : 0;
    hcur[t] = 0;
    __syncthreads();
    for (int j = t; j < CHUNK; j += 256) {
      const int s = src[e0 + j], d = dst[e0 + j];
      const int bk = d >> 8;
      const int pos = bstart[bk] + atomicAdd(&hcur[bk], 1);
      pairs[pos] = make_uint2((unsigned)s, (unsigned)d);
    }
    __syncthreads();
    for (int j = t; j < CHUNK; j += 256) {
      const uint2 pr = pairs[j];
      const int bk = (int)pr.y >> 8;
      slab[(size_t)bk * CAP + gbase[bk] + (j - bstart[bk])] = pr;
    }
    return;
  }
  if (b < CB + XB) {  // x -> bf16 into ab cols 128..255
    int idx = (b - CB) * 256 + t;
    if (idx < NN * 32) {
      int node = idx >> 5, cg = idx & 31;
      float4 v = *(const float4*)(x + (size_t)node * D0 + cg * 4);
      ushort4 o;
      o.x = f2b(v.x); o.y = f2b(v.y); o.z = f2b(v.z); o.w = f2b(v.w);
      *(ushort4*)(ab + (size_t)node * 256 + 128 + cg * 4) = o;
    }
    return;
  }
  if (b < CB + XB + WB) {  // [W1l|W1r] -> bf16 wb[col][256]
    int idx = (b - CB - XB) * 256 + t;
    int c = idx >> 6, k = (idx & 63) * 4;
    const float* srcp = (k < 128) ? (W1l + (size_t)c * 128 + k)
                                  : (W1r + (size_t)c * 128 + (k - 128));
    float4 v = *(const float4*)srcp;
    ushort4 o;
    o.x = f2b(v.x); o.y = f2b(v.y); o.z = f2b(v.z); o.w = f2b(v.w);
    *(ushort4*)(wb + (size_t)c * 256 + k) = o;
    return;
  }
  {  // W2l/W2r -> bf16 w2b[16][256], rows 10..15 = 0
    int idx = (b - CB - XB - WB) * 256 + t;  // [0,1024)
    int n = idx >> 6, k = (idx & 63) * 4;
    float4 v = {0.f, 0.f, 0.f, 0.f};
    if (n < 5) v = *(const float4*)(W2l + (size_t)n * D1 + k);
    else if (n < 10) v = *(const float4*)(W2r + (size_t)(n - 5) * D1 + k);
    ushort4 o;
    o.x = f2b(v.x); o.y = f2b(v.y); o.z = f2b(v.z); o.w = f2b(v.w);
    *(ushort4*)(w2b + (size_t)n * 256 + k) = o;
  }
}

// ------------------- pass BC: per-bucket CSR + LDS-staged coalesced scatter
// 512 threads: halves the stride-loop passes; scans guarded to lanes < 256.
__global__ __launch_bounds__(512) void k_bucketBC(
    const uint2* __restrict__ slab, const int* __restrict__ gcur,
    int* __restrict__ cur, float* __restrict__ inv,
    int* __restrict__ esort) {
  __shared__ int cnt[BSZ], s[BSZ], lcur[BSZ], g[256];
  __shared__ int sorted[CAP];  // 19.2 KB: LDS-staged sorted bucket
  const int b = blockIdx.x, t = threadIdx.x;
  const int n0 = b << 8;
  if (t < BSZ) cnt[t] = 0;
  if (t < 256) g[t] = (t < NBUK) ? gcur[t] : 0;
  __syncthreads();
  for (int dd = 1; dd < 256; dd <<= 1) {
    int u = (t >= dd && t < 256) ? g[t - dd] : 0;
    __syncthreads();
    if (t < 256) g[t] += u;
    __syncthreads();
  }
  const int bbase = (b == 0) ? 0 : g[b - 1];
  const int cntE = gcur[b];
  const uint2* sp = slab + (size_t)b * CAP;
  for (int j = t; j < cntE; j += 512)
    atomicAdd(&cnt[(int)sp[j].y - n0], 1);
  __syncthreads();
  if (t < BSZ) s[t] = cnt[t];
  __syncthreads();
  for (int dd = 1; dd < BSZ; dd <<= 1) {
    int u = (t >= dd && t < BSZ) ? s[t - dd] : 0;
    __syncthreads();
    if (t < BSZ) s[t] += u;
    __syncthreads();
  }
  if (t < BSZ) {
    const int start = bbase + (s[t] - cnt[t]);
    const int node = n0 + t;
    if (node < NN) {
      cur[node] = start;
      inv[node] = 1.0f / (float)max(cnt[t], 1);
    }
    lcur[t] = s[t] - cnt[t];  // LOCAL offset within bucket
  }
  if (b == NBUK - 1 && t == 0) cur[NN] = NE;
  __syncthreads();
  for (int j = t; j < cntE; j += 512) {
    const uint2 pr = sp[j];
    const int p = atomicAdd(&lcur[(int)pr.y - n0], 1);
    sorted[p] = (int)pr.x;  // random LDS write (cheap)
  }
  __syncthreads();
  for (int j = t; j < cntE; j += 512)  // coalesced global stream-out
    esort[bbase + j] = sorted[j];
}

// ---------------------------------------------------------------- aggregate 1
// 1 wave per node; 64 lanes x 4B = one 256B contiguous segment per edge.
// Line floor (r0-r2 triangulation): ~15 cyc per 128B line per CU ->
// 1.6M lines / 256 CUs ~= 94k cyc ~= 39us. This layout is at that floor.
__global__ __launch_bounds__(256) void k_agg1(
    unsigned short* __restrict__ ab, const int* __restrict__ esort,
    const int* __restrict__ cur, const float* __restrict__ inv) {
  const int i = (blockIdx.x * 256 + threadIdx.x) >> 6;
  const int lane = threadIdx.x & 63;
  if (i >= NN) return;
  int e = cur[i];
  const int end = cur[i + 1];
  float a0 = 0.f, b0 = 0.f, a1 = 0.f, b1 = 0.f;
  float a2 = 0.f, b2 = 0.f, a3 = 0.f, b3 = 0.f;
  const unsigned short* xb = ab + 128 + lane * 2;
  while (e < end && (e & 3)) {
    const unsigned v = *(const unsigned*)(xb + (size_t)esort[e] * 256);
    a0 += b2f((unsigned short)v); b0 += b2f((unsigned short)(v >> 16));
    ++e;
  }
  for (; e + 7 < end; e += 8) {
    const int4 s0 = *(const int4*)(esort + e);
    const int4 s1 = *(const int4*)(esort + e + 4);
    const unsigned v0 = *(const unsigned*)(xb + (size_t)s0.x * 256);
    const unsigned v1 = *(const unsigned*)(xb + (size_t)s0.y * 256);
    const unsigned v2 = *(const unsigned*)(xb + (size_t)s0.z * 256);
    const unsigned v3 = *(const unsigned*)(xb + (size_t)s0.w * 256);
    const unsigned v4 = *(const unsigned*)(xb + (size_t)s1.x * 256);
    const unsigned v5 = *(const unsigned*)(xb + (size_t)s1.y * 256);
    const unsigned v6 = *(const unsigned*)(xb + (size_t)s1.z * 256);
    const unsigned v7 = *(const unsigned*)(xb + (size_t)s1.w * 256);
    a0 += b2f((unsigned short)v0); b0 += b2f((unsigned short)(v0 >> 16));
    a1 += b2f((unsigned short)v1); b1 += b2f((unsigned short)(v1 >> 16));
    a2 += b2f((unsigned short)v2); b2 += b2f((unsigned short)(v2 >> 16));
    a3 += b2f((unsigned short)v3); b3 += b2f((unsigned short)(v3 >> 16));
    a0 += b2f((unsigned short)v4); b0 += b2f((unsigned short)(v4 >> 16));
    a1 += b2f((unsigned short)v5); b1 += b2f((unsigned short)(v5 >> 16));
    a2 += b2f((unsigned short)v6); b2 += b2f((unsigned short)(v6 >> 16));
    a3 += b2f((unsigned short)v7); b3 += b2f((unsigned short)(v7 >> 16));
  }
  if (e + 3 < end) {
    const int4 s0 = *(const int4*)(esort + e);
    const unsigned v0 = *(const unsigned*)(xb + (size_t)s0.x * 256);
    const unsigned v1 = *(const unsigned*)(xb + (size_t)s0.y * 256);
    const unsigned v2 = *(const unsigned*)(xb + (size_t)s0.z * 256);
    const unsigned v3 = *(const unsigned*)(xb + (size_t)s0.w * 256);
    a0 += b2f((unsigned short)v0); b0 += b2f((unsigned short)(v0 >> 16));
    a1 += b2f((unsigned short)v1); b1 += b2f((unsigned short)(v1 >> 16));
    a2 += b2f((unsigned short)v2); b2 += b2f((unsigned short)(v2 >> 16));
    a3 += b2f((unsigned short)v3); b3 += b2f((unsigned short)(v3 >> 16));
    e += 4;
  }
  for (; e < end; ++e) {
    const unsigned v = *(const unsigned*)(xb + (size_t)esort[e] * 256);
    a0 += b2f((unsigned short)v); b0 += b2f((unsigned short)(v >> 16));
  }
  const float sc = inv[i];
  const float sa = (a0 + a1) + (a2 + a3);
  const float sb = (b0 + b1) + (b2 + b3);
  const unsigned out =
      ((unsigned)f2b(sb * sc) << 16) | (unsigned)f2b(sa * sc);
  *(unsigned*)(ab + (size_t)i * 256 + lane * 2) = out;
}

// ------------------------------------- GEMM 1 + fused layer-2 linear (MFMA)
__global__ __launch_bounds__(256) void k_gemm1f(
    const unsigned short* __restrict__ ab, const unsigned short* __restrict__ wb,
    const unsigned short* __restrict__ w2b, const float* __restrict__ b1l,
    float* __restrict__ tt, float* __restrict__ rp) {
  __shared__ short sAB[2 * 128 * 72];  // sA | sB, later reused as sH[128][136]
  short* sA = sAB;
  short* sB = sAB + 128 * 72;
  const int tid = threadIdx.x;
  const int row0 = blockIdx.y * 128;
  const int hf = blockIdx.x;
  const int col0 = hf * 128;
  const int wave = tid >> 6, lane = tid & 63;
  const int quad = lane >> 4, m16 = lane & 15;
  const int wm = wave & 1, wn = wave >> 1;
  const int lr = tid >> 2;
  const int lk = (tid & 3) * 8;

  floatx4 acc[4][4];
#pragma unroll
  for (int a = 0; a < 4; ++a)
#pragma unroll
    for (int b = 0; b < 4; ++b) acc[a][b] = {0.f, 0.f, 0.f, 0.f};

  const int gr0 = row0 + lr, gr1 = row0 + lr + 64;
  const bool ok0 = gr0 < NN, ok1 = gr1 < NN;
  const unsigned short* aptr0 = ab + (size_t)gr0 * 256 + lk;
  const unsigned short* aptr1 = ab + (size_t)gr1 * 256 + lk;
  const unsigned short* bptr0 = wb + (size_t)(col0 + lr) * 256 + lk;
  const unsigned short* bptr1 = wb + (size_t)(col0 + lr + 64) * 256 + lk;
  short* sA0 = &sA[lr * 72 + lk];
  short* sA1 = &sA[(lr + 64) * 72 + lk];
  short* sB0 = &sB[lr * 72 + lk];
  short* sB1 = &sB[(lr + 64) * 72 + lk];
  const uint4 zz = make_uint4(0, 0, 0, 0);

  uint4 a00 = ok0 ? *(const uint4*)(aptr0) : zz;
  uint4 a01 = ok0 ? *(const uint4*)(aptr0 + 32) : zz;
  uint4 a10 = ok1 ? *(const uint4*)(aptr1) : zz;
  uint4 a11 = ok1 ? *(const uint4*)(aptr1 + 32) : zz;
  uint4 b00 = *(const uint4*)(bptr0);
  uint4 b01 = *(const uint4*)(bptr0 + 32);
  uint4 b10 = *(const uint4*)(bptr1);
  uint4 b11 = *(const uint4*)(bptr1 + 32);

  for (int kk = 0; kk < 256; kk += 64) {
    __syncthreads();
    *(uint4*)sA0 = a00;
    *(uint4*)(sA0 + 32) = a01;
    *(uint4*)sA1 = a10;
    *(uint4*)(sA1 + 32) = a11;
    *(uint4*)sB0 = b00;
    *(uint4*)(sB0 + 32) = b01;
    *(uint4*)sB1 = b10;
    *(uint4*)(sB1 + 32) = b11;
    __syncthreads();
    if (kk < 192) {
      const int kn = kk + 64;
      a00 = ok0 ? *(const uint4*)(aptr0 + kn) : zz;
      a01 = ok0 ? *(const uint4*)(aptr0 + kn + 32) : zz;
      a10 = ok1 ? *(const uint4*)(aptr1 + kn) : zz;
      a11 = ok1 ? *(const uint4*)(aptr1 + kn + 32) : zz;
      b00 = *(const uint4*)(bptr0 + kn);
      b01 = *(const uint4*)(bptr0 + kn + 32);
      b10 = *(const uint4*)(bptr1 + kn);
      b11 = *(const uint4*)(bptr1 + kn + 32);
    }
#pragma unroll
    for (int ko = 0; ko < 64; ko += 32) {
      short8 af[4], bf[4];
#pragma unroll
      for (int mt = 0; mt < 4; ++mt)
        af[mt] =
            *(const short8*)&sA[(wm * 64 + mt * 16 + m16) * 72 + ko + quad * 8];
#pragma unroll
      for (int nt = 0; nt < 4; ++nt)
        bf[nt] =
            *(const short8*)&sB[(wn * 64 + nt * 16 + m16) * 72 + ko + quad * 8];
#pragma unroll
      for (int mt = 0; mt < 4; ++mt)
#pragma unroll
        for (int nt = 0; nt < 4; ++nt)
          acc[mt][nt] = __builtin_amdgcn_mfma_f32_16x16x32_bf16(
              af[mt], bf[nt], acc[mt][nt], 0, 0, 0);
    }
  }

  __syncthreads();
  short* sH = sAB;  // [128][136]
#pragma unroll
  for (int nt = 0; nt < 4; ++nt) {
    const int cl = wn * 64 + nt * 16 + m16;
    const float bias = b1l[col0 + cl];
#pragma unroll
    for (int mt = 0; mt < 4; ++mt)
#pragma unroll
      for (int rg = 0; rg < 4; ++rg) {
        const int rl = wm * 64 + mt * 16 + quad * 4 + rg;
        sH[rl * 136 + cl] = (short)f2b(fmaxf(acc[mt][nt][rg] + bias, 0.f));
      }
  }
  __syncthreads();
  floatx4 c2[2] = {{0.f, 0.f, 0.f, 0.f}, {0.f, 0.f, 0.f, 0.f}};
#pragma unroll
  for (int kb = 0; kb < 4; ++kb) {
    const short8 bf2 =
        *(const short8*)&w2b[m16 * 256 + col0 + kb * 32 + quad * 8];
#pragma unroll
    for (int i = 0; i < 2; ++i) {
      const int mrow = (wave * 2 + i) * 16 + m16;
      const short8 af2 = *(const short8*)&sH[mrow * 136 + kb * 32 + quad * 8];
      c2[i] = __builtin_amdgcn_mfma_f32_16x16x32_bf16(af2, bf2, c2[i], 0, 0, 0);
    }
  }
#pragma unroll
  for (int i = 0; i < 2; ++i) {
    const int rbase = row0 + (wave * 2 + i) * 16 + quad * 4;
#pragma unroll
    for (int rg = 0; rg < 4; ++rg) {
      const int row = rbase + rg;
      if (row < NN) {
        if (m16 < 5)
          tt[(size_t)row * 16 + hf * 8 + m16] = c2[i][rg];
        else if (m16 < 10)
          rp[(size_t)hf * ((size_t)NN * 8) + (size_t)row * 8 + (m16 - 5)] =
              c2[i][rg];
      }
    }
  }
}

// ---------------- layer-2 aggregate: 16 lanes COOPERATE on one edge row.
// lane = dim; per edge one 64B contiguous segment. Reduce = single shfl_xor(8).
// Line floor: 800k lines / 256 CUs * 15 cyc ~= 47k cyc ~= 20us — at floor.
__global__ __launch_bounds__(256) void k_layer2(
    const float* __restrict__ tt, const float* __restrict__ rp,
    const int* __restrict__ esort, const int* __restrict__ cur,
    const float* __restrict__ inv, const float* __restrict__ b2l,
    float* __restrict__ out) {
  const int node = blockIdx.x * 16 + (threadIdx.x >> 4);
  const int l = threadIdx.x & 15;
  if (node >= NN) return;
  const int beg = cur[node], end = cur[node + 1];
  float s = 0.f, u = 0.f;
  int e = beg;
  for (; e + 3 < end; e += 4) {  // 4-deep ILP
    const int4 r4 = *(const int4*)(esort + e);
    const float t0 = tt[(size_t)r4.x * 16 + l];
    const float t1 = tt[(size_t)r4.y * 16 + l];
    const float t2 = tt[(size_t)r4.z * 16 + l];
    const float t3 = tt[(size_t)r4.w * 16 + l];
    s += t0 + t2;
    u += t1 + t3;
  }
  for (; e < end; ++e) s += tt[(size_t)esort[e] * 16 + l];
  s += u;
  s += __shfl_xor(s, 8, 64);  // combine K-half at pos l and l+8
  if (l < 5) {
    const float r = rp[(size_t)node * 8 + l] +
                    rp[(size_t)NN * 8 + (size_t)node * 8 + l];
    out[(size_t)node * D2 + l] = fmaxf(s * inv[node] + b2l[l] + r, 0.f);
  }
}

extern "C" void kernel_launch(void* const* d_in, const int* in_sizes, int n_in,
                              void* d_out, int out_size, void* d_ws,
                              size_t ws_size, hipStream_t stream) {
  const float* x   = (const float*)d_in[0];
  const int*   ei  = (const int*)d_in[1];
  const int*   src = ei;
  const int*   dst = ei + NE;
  const float* W1l = (const float*)d_in[2];
  const float* b1l = (const float*)d_in[3];
  const float* W1r = (const float*)d_in[4];
  const float* W2l = (const float*)d_in[5];
  const float* b2l = (const float*)d_in[6];
  const float* W2r = (const float*)d_in[7];
  float* out = (float*)d_out;

  // workspace layout: big aligned arrays first (16B-aligned offsets)
  unsigned short* ab  = (unsigned short*)d_ws;          // NN*256 bf16
  unsigned short* wb  = ab + (size_t)NN * 256;          // 256*256 bf16
  unsigned short* w2b = wb + 256 * 256;                 // 16*256 bf16
  float* tt   = (float*)(w2b + 16 * 256);               // NN*16 (t interleaved)
  float* rp   = tt + (size_t)NN * 16;                   // 2 * NN*8 (r partials)
  uint2* slab = (uint2*)(rp + (size_t)NN * 16);         // NBUK*CAP pairs
  int*   gcur = (int*)(slab + (size_t)NBUK * CAP);      // 256
  int*   esort = gcur + 256;                            // NE (16B aligned)
  int*   cur  = esort + NE;                             // NN+1 (+3 pad)
  float* inv  = (float*)(cur + NN + 4);                 // NN

  hipMemsetAsync(gcur, 0, 256 * sizeof(int), stream);

  k_prepA<<<CB + XB + WB + PB, 256, 0, stream>>>(x, ab, W1l, W1r, wb, W2l, W2r,
                                                 w2b, src, dst, gcur, slab);
  k_bucketBC<<<NBUK, 512, 0, stream>>>(slab, gcur, cur, inv, esort);
  k_agg1<<<(NN * 64 + 255) / 256, 256, 0, stream>>>(ab, esort, cur, inv);
  dim3 g1(2, (NN + 127) / 128);
  k_gemm1f<<<g1, 256, 0, stream>>>(ab, wb, w2b, b1l, tt, rp);
  k_layer2<<<(NN + 15) / 16, 256, 0, stream>>>(tt, rp, esort, cur, inv, b2l,
                                               out);
}

// Round 7
// 166.192 us; speedup vs baseline: 3.6402x; 1.0623x over previous
//
#include <hip/hip_runtime.h>

static constexpr int NN = 50000;   // nodes
static constexpr int NE = 800000;  // edges
static constexpr int D0 = 128;     // in dim
static constexpr int D1 = 256;     // hidden
static constexpr int D2 = 5;       // out

// bucketed edge sort: BSZ pow2 so bucket = dst>>8
static constexpr int BSZ   = 256;                  // nodes per bucket
static constexpr int NBUK  = (NN + BSZ - 1) / BSZ; // 196
static constexpr int CAP   = 4800;   // slab cap (mean 4081, +11 sigma)
static constexpr int CB    = 256;    // chunk blocks: exactly 1 per CU (no tail)
static constexpr int CHUNK = 3125;   // edges per chunk (CB*CHUNK == NE)

// prepA grid partition: bucketA FIRST (heavy blocks dispatch early)
static constexpr int XB = (NN * 32 + 255) / 256;   // 6250 cvtx blocks
static constexpr int WB = (D1 * 64) / 256;         // 64 cvtw blocks
static constexpr int PB = 4;                       // w2b convert blocks

using short8  = __attribute__((ext_vector_type(8))) short;
using floatx4 = __attribute__((ext_vector_type(4))) float;

__device__ __forceinline__ unsigned short f2b(float f) {
  union { float f; unsigned u; } v; v.f = f;
  unsigned r = v.u + 0x7fffu + ((v.u >> 16) & 1u);  // RNE
  return (unsigned short)(r >> 16);
}
__device__ __forceinline__ float b2f(unsigned short s) {
  union { unsigned u; float f; } v; v.u = ((unsigned)s) << 16;
  return v.f;
}
__device__ __forceinline__ float blo(unsigned u) {  // bf16 in bits 0-15
  union { unsigned u; float f; } v; v.u = u << 16;
  return v.f;
}
__device__ __forceinline__ float bhi(unsigned u) {  // bf16 in bits 16-31
  union { unsigned u; float f; } v; v.u = u & 0xffff0000u;
  return v.f;
}

// ---------------- fused prep: bucketA (first) | cvtx | cvtw1 | cvtw2
__global__ __launch_bounds__(256) void k_prepA(
    const float* __restrict__ x, unsigned short* __restrict__ ab,
    const float* __restrict__ W1l, const float* __restrict__ W1r,
    unsigned short* __restrict__ wb, const float* __restrict__ W2l,
    const float* __restrict__ W2r, unsigned short* __restrict__ w2b,
    const int* __restrict__ src, const int* __restrict__ dst,
    int* __restrict__ gcur, uint2* __restrict__ slab) {
  __shared__ int hist[256], bstart[256], gbase[256], hcur[256], sscan[256];
  __shared__ uint2 pairs[CHUNK];  // 25 KB
  const int b = blockIdx.x, t = threadIdx.x;
  if (b < CB) {  // ---- bucketA: chunk -> LDS bucket-sort -> contiguous slab
    const int e0 = b * CHUNK;
    hist[t] = 0;
    __syncthreads();
    for (int j = t; j < CHUNK; j += 256)
      atomicAdd(&hist[dst[e0 + j] >> 8], 1);
    __syncthreads();
    sscan[t] = hist[t];
    __syncthreads();
    for (int dd = 1; dd < 256; dd <<= 1) {
      int u = (t >= dd) ? sscan[t - dd] : 0;
      __syncthreads();
      sscan[t] += u;
      __syncthreads();
    }
    bstart[t] = sscan[t] - hist[t];
    gbase[t] = (t < NBUK && hist[t] > 0) ? atomicAdd(&gcur[t], hist[t]) : 0;
    hcur[t] = 0;
    __syncthreads();
    for (int j = t; j < CHUNK; j += 256) {
      const int s = src[e0 + j], d = dst[e0 + j];
      const int bk = d >> 8;
      const int pos = bstart[bk] + atomicAdd(&hcur[bk], 1);
      pairs[pos] = make_uint2((unsigned)s, (unsigned)d);
    }
    __syncthreads();
    for (int j = t; j < CHUNK; j += 256) {
      const uint2 pr = pairs[j];
      const int bk = (int)pr.y >> 8;
      slab[(size_t)bk * CAP + gbase[bk] + (j - bstart[bk])] = pr;
    }
    return;
  }
  if (b < CB + XB) {  // x -> bf16 into ab cols 128..255
    int idx = (b - CB) * 256 + t;
    if (idx < NN * 32) {
      int node = idx >> 5, cg = idx & 31;
      float4 v = *(const float4*)(x + (size_t)node * D0 + cg * 4);
      ushort4 o;
      o.x = f2b(v.x); o.y = f2b(v.y); o.z = f2b(v.z); o.w = f2b(v.w);
      *(ushort4*)(ab + (size_t)node * 256 + 128 + cg * 4) = o;
    }
    return;
  }
  if (b < CB + XB + WB) {  // [W1l|W1r] -> bf16 wb[col][256]
    int idx = (b - CB - XB) * 256 + t;
    int c = idx >> 6, k = (idx & 63) * 4;
    const float* srcp = (k < 128) ? (W1l + (size_t)c * 128 + k)
                                  : (W1r + (size_t)c * 128 + (k - 128));
    float4 v = *(const float4*)srcp;
    ushort4 o;
    o.x = f2b(v.x); o.y = f2b(v.y); o.z = f2b(v.z); o.w = f2b(v.w);
    *(ushort4*)(wb + (size_t)c * 256 + k) = o;
    return;
  }
  {  // W2l/W2r -> bf16 w2b[16][256], rows 10..15 = 0
    int idx = (b - CB - XB - WB) * 256 + t;  // [0,1024)
    int n = idx >> 6, k = (idx & 63) * 4;
    float4 v = {0.f, 0.f, 0.f, 0.f};
    if (n < 5) v = *(const float4*)(W2l + (size_t)n * D1 + k);
    else if (n < 10) v = *(const float4*)(W2r + (size_t)(n - 5) * D1 + k);
    ushort4 o;
    o.x = f2b(v.x); o.y = f2b(v.y); o.z = f2b(v.z); o.w = f2b(v.w);
    *(ushort4*)(w2b + (size_t)n * 256 + k) = o;
  }
}

// ------------------- pass BC: per-bucket CSR + LDS-staged coalesced scatter
// 512 threads: halves the stride-loop passes; scans guarded to lanes < 256.
__global__ __launch_bounds__(512) void k_bucketBC(
    const uint2* __restrict__ slab, const int* __restrict__ gcur,
    int* __restrict__ cur, float* __restrict__ inv,
    int* __restrict__ esort) {
  __shared__ int cnt[BSZ], s[BSZ], lcur[BSZ], g[256];
  __shared__ int sorted[CAP];  // 19.2 KB: LDS-staged sorted bucket
  const int b = blockIdx.x, t = threadIdx.x;
  const int n0 = b << 8;
  if (t < BSZ) cnt[t] = 0;
  if (t < 256) g[t] = (t < NBUK) ? gcur[t] : 0;
  __syncthreads();
  for (int dd = 1; dd < 256; dd <<= 1) {
    int u = (t >= dd && t < 256) ? g[t - dd] : 0;
    __syncthreads();
    if (t < 256) g[t] += u;
    __syncthreads();
  }
  const int bbase = (b == 0) ? 0 : g[b - 1];
  const int cntE = gcur[b];
  const uint2* sp = slab + (size_t)b * CAP;
  for (int j = t; j < cntE; j += 512)
    atomicAdd(&cnt[(int)sp[j].y - n0], 1);
  __syncthreads();
  if (t < BSZ) s[t] = cnt[t];
  __syncthreads();
  for (int dd = 1; dd < BSZ; dd <<= 1) {
    int u = (t >= dd && t < BSZ) ? s[t - dd] : 0;
    __syncthreads();
    if (t < BSZ) s[t] += u;
    __syncthreads();
  }
  if (t < BSZ) {
    const int start = bbase + (s[t] - cnt[t]);
    const int node = n0 + t;
    if (node < NN) {
      cur[node] = start;
      inv[node] = 1.0f / (float)max(cnt[t], 1);
    }
    lcur[t] = s[t] - cnt[t];  // LOCAL offset within bucket
  }
  if (b == NBUK - 1 && t == 0) cur[NN] = NE;
  __syncthreads();
  for (int j = t; j < cntE; j += 512) {
    const uint2 pr = sp[j];
    const int p = atomicAdd(&lcur[(int)pr.y - n0], 1);
    sorted[p] = (int)pr.x;  // random LDS write (cheap)
  }
  __syncthreads();
  for (int j = t; j < cntE; j += 512)  // coalesced global stream-out
    esort[bbase + j] = sorted[j];
}

// ---------------------------------------------------------------- aggregate 1
// 1 wave per node, 4 rows per GATHER INSTRUCTION: lane = (edge-slot r=lane>>4,
// 16B chunk q=lane&15); per-lane dwordx4 fetches 4 complete 256B rows per
// instruction (vs 1 row/instr before). Line-touches unchanged (2/edge, the
// data floor); instruction count / address VALU cut 4x — probes whether the
// ~30cyc/gather-instr cost (r0-r2) has a per-instruction component.
// Tail: clamp index to last edge + zero-mask (no divergence, no extra lines).
__global__ __launch_bounds__(256) void k_agg1(
    unsigned short* __restrict__ ab, const int* __restrict__ esort,
    const int* __restrict__ cur, const float* __restrict__ inv) {
  const int i = (blockIdx.x * 256 + threadIdx.x) >> 6;
  if (i >= NN) return;
  const int lane = threadIdx.x & 63;
  const int r = lane >> 4;   // edge slot 0..3
  const int q = lane & 15;   // 16B chunk: dims q*8 .. q*8+7
  const int beg = cur[i], end = cur[i + 1];
  const int last = end - 1;
  const unsigned short* xb = ab + 128 + q * 8;  // gather base (cols 128..255)
  float a0 = 0.f, a1 = 0.f, a2 = 0.f, a3 = 0.f;
  float a4 = 0.f, a5 = 0.f, a6 = 0.f, a7 = 0.f;
  const uint4 zz = make_uint4(0, 0, 0, 0);
  for (int e = beg; e < end; e += 8) {
    const int i0 = e + r, i1 = e + 4 + r;
    const int x0 = esort[min(i0, last)];
    const int x1 = esort[min(i1, last)];
    uint4 v0 = *(const uint4*)(xb + (size_t)x0 * 256);
    uint4 v1 = *(const uint4*)(xb + (size_t)x1 * 256);
    if (i0 > last) v0 = zz;
    if (i1 > last) v1 = zz;
    a0 += blo(v0.x); a1 += bhi(v0.x);
    a2 += blo(v0.y); a3 += bhi(v0.y);
    a4 += blo(v0.z); a5 += bhi(v0.z);
    a6 += blo(v0.w); a7 += bhi(v0.w);
    a0 += blo(v1.x); a1 += bhi(v1.x);
    a2 += blo(v1.y); a3 += bhi(v1.y);
    a4 += blo(v1.z); a5 += bhi(v1.z);
    a6 += blo(v1.w); a7 += bhi(v1.w);
  }
  // combine the 4 edge slots (lanes r, r^1, r^2): xor-16 then xor-32
  a0 += __shfl_xor(a0, 16, 64); a1 += __shfl_xor(a1, 16, 64);
  a2 += __shfl_xor(a2, 16, 64); a3 += __shfl_xor(a3, 16, 64);
  a4 += __shfl_xor(a4, 16, 64); a5 += __shfl_xor(a5, 16, 64);
  a6 += __shfl_xor(a6, 16, 64); a7 += __shfl_xor(a7, 16, 64);
  a0 += __shfl_xor(a0, 32, 64); a1 += __shfl_xor(a1, 32, 64);
  a2 += __shfl_xor(a2, 32, 64); a3 += __shfl_xor(a3, 32, 64);
  a4 += __shfl_xor(a4, 32, 64); a5 += __shfl_xor(a5, 32, 64);
  a6 += __shfl_xor(a6, 32, 64); a7 += __shfl_xor(a7, 32, 64);
  if (r == 0) {  // lanes 0..15 write the full 256B mean row (cols 0..127)
    const float sc = inv[i];
    uint4 o;
    o.x = ((unsigned)f2b(a1 * sc) << 16) | (unsigned)f2b(a0 * sc);
    o.y = ((unsigned)f2b(a3 * sc) << 16) | (unsigned)f2b(a2 * sc);
    o.z = ((unsigned)f2b(a5 * sc) << 16) | (unsigned)f2b(a4 * sc);
    o.w = ((unsigned)f2b(a7 * sc) << 16) | (unsigned)f2b(a6 * sc);
    *(uint4*)(ab + (size_t)i * 256 + q * 8) = o;
  }
}

// ------------------------------------- GEMM 1 + fused layer-2 linear (MFMA)
__global__ __launch_bounds__(256) void k_gemm1f(
    const unsigned short* __restrict__ ab, const unsigned short* __restrict__ wb,
    const unsigned short* __restrict__ w2b, const float* __restrict__ b1l,
    float* __restrict__ tt, float* __restrict__ rp) {
  __shared__ short sAB[2 * 128 * 72];  // sA | sB, later reused as sH[128][136]
  short* sA = sAB;
  short* sB = sAB + 128 * 72;
  const int tid = threadIdx.x;
  const int row0 = blockIdx.y * 128;
  const int hf = blockIdx.x;
  const int col0 = hf * 128;
  const int wave = tid >> 6, lane = tid & 63;
  const int quad = lane >> 4, m16 = lane & 15;
  const int wm = wave & 1, wn = wave >> 1;
  const int lr = tid >> 2;
  const int lk = (tid & 3) * 8;

  floatx4 acc[4][4];
#pragma unroll
  for (int a = 0; a < 4; ++a)
#pragma unroll
    for (int b = 0; b < 4; ++b) acc[a][b] = {0.f, 0.f, 0.f, 0.f};

  const int gr0 = row0 + lr, gr1 = row0 + lr + 64;
  const bool ok0 = gr0 < NN, ok1 = gr1 < NN;
  const unsigned short* aptr0 = ab + (size_t)gr0 * 256 + lk;
  const unsigned short* aptr1 = ab + (size_t)gr1 * 256 + lk;
  const unsigned short* bptr0 = wb + (size_t)(col0 + lr) * 256 + lk;
  const unsigned short* bptr1 = wb + (size_t)(col0 + lr + 64) * 256 + lk;
  short* sA0 = &sA[lr * 72 + lk];
  short* sA1 = &sA[(lr + 64) * 72 + lk];
  short* sB0 = &sB[lr * 72 + lk];
  short* sB1 = &sB[(lr + 64) * 72 + lk];
  const uint4 zz = make_uint4(0, 0, 0, 0);

  uint4 a00 = ok0 ? *(const uint4*)(aptr0) : zz;
  uint4 a01 = ok0 ? *(const uint4*)(aptr0 + 32) : zz;
  uint4 a10 = ok1 ? *(const uint4*)(aptr1) : zz;
  uint4 a11 = ok1 ? *(const uint4*)(aptr1 + 32) : zz;
  uint4 b00 = *(const uint4*)(bptr0);
  uint4 b01 = *(const uint4*)(bptr0 + 32);
  uint4 b10 = *(const uint4*)(bptr1);
  uint4 b11 = *(const uint4*)(bptr1 + 32);

  for (int kk = 0; kk < 256; kk += 64) {
    __syncthreads();
    *(uint4*)sA0 = a00;
    *(uint4*)(sA0 + 32) = a01;
    *(uint4*)sA1 = a10;
    *(uint4*)(sA1 + 32) = a11;
    *(uint4*)sB0 = b00;
    *(uint4*)(sB0 + 32) = b01;
    *(uint4*)sB1 = b10;
    *(uint4*)(sB1 + 32) = b11;
    __syncthreads();
    if (kk < 192) {
      const int kn = kk + 64;
      a00 = ok0 ? *(const uint4*)(aptr0 + kn) : zz;
      a01 = ok0 ? *(const uint4*)(aptr0 + kn + 32) : zz;
      a10 = ok1 ? *(const uint4*)(aptr1 + kn) : zz;
      a11 = ok1 ? *(const uint4*)(aptr1 + kn + 32) : zz;
      b00 = *(const uint4*)(bptr0 + kn);
      b01 = *(const uint4*)(bptr0 + kn + 32);
      b10 = *(const uint4*)(bptr1 + kn);
      b11 = *(const uint4*)(bptr1 + kn + 32);
    }
#pragma unroll
    for (int ko = 0; ko < 64; ko += 32) {
      short8 af[4], bf[4];
#pragma unroll
      for (int mt = 0; mt < 4; ++mt)
        af[mt] =
            *(const short8*)&sA[(wm * 64 + mt * 16 + m16) * 72 + ko + quad * 8];
#pragma unroll
      for (int nt = 0; nt < 4; ++nt)
        bf[nt] =
            *(const short8*)&sB[(wn * 64 + nt * 16 + m16) * 72 + ko + quad * 8];
#pragma unroll
      for (int mt = 0; mt < 4; ++mt)
#pragma unroll
        for (int nt = 0; nt < 4; ++nt)
          acc[mt][nt] = __builtin_amdgcn_mfma_f32_16x16x32_bf16(
              af[mt], bf[nt], acc[mt][nt], 0, 0, 0);
    }
  }

  __syncthreads();
  short* sH = sAB;  // [128][136]
#pragma unroll
  for (int nt = 0; nt < 4; ++nt) {
    const int cl = wn * 64 + nt * 16 + m16;
    const float bias = b1l[col0 + cl];
#pragma unroll
    for (int mt = 0; mt < 4; ++mt)
#pragma unroll
      for (int rg = 0; rg < 4; ++rg) {
        const int rl = wm * 64 + mt * 16 + quad * 4 + rg;
        sH[rl * 136 + cl] = (short)f2b(fmaxf(acc[mt][nt][rg] + bias, 0.f));
      }
  }
  __syncthreads();
  floatx4 c2[2] = {{0.f, 0.f, 0.f, 0.f}, {0.f, 0.f, 0.f, 0.f}};
#pragma unroll
  for (int kb = 0; kb < 4; ++kb) {
    const short8 bf2 =
        *(const short8*)&w2b[m16 * 256 + col0 + kb * 32 + quad * 8];
#pragma unroll
    for (int i = 0; i < 2; ++i) {
      const int mrow = (wave * 2 + i) * 16 + m16;
      const short8 af2 = *(const short8*)&sH[mrow * 136 + kb * 32 + quad * 8];
      c2[i] = __builtin_amdgcn_mfma_f32_16x16x32_bf16(af2, bf2, c2[i], 0, 0, 0);
    }
  }
#pragma unroll
  for (int i = 0; i < 2; ++i) {
    const int rbase = row0 + (wave * 2 + i) * 16 + quad * 4;
#pragma unroll
    for (int rg = 0; rg < 4; ++rg) {
      const int row = rbase + rg;
      if (row < NN) {
        if (m16 < 5)
          tt[(size_t)row * 16 + hf * 8 + m16] = c2[i][rg];
        else if (m16 < 10)
          rp[(size_t)hf * ((size_t)NN * 8) + (size_t)row * 8 + (m16 - 5)] =
              c2[i][rg];
      }
    }
  }
}

// ---------------- layer-2 aggregate: 4 lanes per edge row, float4 loads ->
// 16 edges per gather instruction (vs 4). Line-touches unchanged (1/edge).
// 16-lane node group: r = edge slot (4), q = 16B chunk (4 floats).
__global__ __launch_bounds__(256) void k_layer2(
    const float* __restrict__ tt, const float* __restrict__ rp,
    const int* __restrict__ esort, const int* __restrict__ cur,
    const float* __restrict__ inv, const float* __restrict__ b2l,
    float* __restrict__ out) {
  const int node = blockIdx.x * 16 + (threadIdx.x >> 4);
  if (node >= NN) return;
  const int t16 = threadIdx.x & 15;
  const int r = t16 >> 2;   // edge slot 0..3
  const int q = t16 & 3;    // float4 chunk: dims q*4 .. q*4+3
  const int beg = cur[node], end = cur[node + 1];
  const int last = end - 1;
  const float* tb = tt + q * 4;
  float s0 = 0.f, s1 = 0.f, s2 = 0.f, s3 = 0.f;
  float u0 = 0.f, u1 = 0.f, u2 = 0.f, u3 = 0.f;
  for (int e = beg; e < end; e += 8) {
    const int i0 = e + r, i1 = e + 4 + r;
    const int x0 = esort[min(i0, last)];
    const int x1 = esort[min(i1, last)];
    float4 v0 = *(const float4*)(tb + (size_t)x0 * 16);
    float4 v1 = *(const float4*)(tb + (size_t)x1 * 16);
    if (i0 > last) v0 = make_float4(0.f, 0.f, 0.f, 0.f);
    if (i1 > last) v1 = make_float4(0.f, 0.f, 0.f, 0.f);
    s0 += v0.x; s1 += v0.y; s2 += v0.z; s3 += v0.w;
    u0 += v1.x; u1 += v1.y; u2 += v1.z; u3 += v1.w;
  }
  s0 += u0; s1 += u1; s2 += u2; s3 += u3;
  // reduce over the 4 edge slots (xor 4, then 8 — stays inside 16-lane group)
  s0 += __shfl_xor(s0, 4, 64); s1 += __shfl_xor(s1, 4, 64);
  s2 += __shfl_xor(s2, 4, 64); s3 += __shfl_xor(s3, 4, 64);
  s0 += __shfl_xor(s0, 8, 64); s1 += __shfl_xor(s1, 8, 64);
  s2 += __shfl_xor(s2, 8, 64); s3 += __shfl_xor(s3, 8, 64);
  // combine K-halves: dim d (lanes q=0,1) + dim d+8 (lanes q=2,3)
  s0 += __shfl_xor(s0, 2, 64); s1 += __shfl_xor(s1, 2, 64);
  s2 += __shfl_xor(s2, 2, 64); s3 += __shfl_xor(s3, 2, 64);
  if (r == 0 && q < 2) {
    const float sc = inv[node];
    const float* r0p = rp + (size_t)node * 8;
    const float* r1p = rp + (size_t)NN * 8 + (size_t)node * 8;
    if (q == 0) {
      out[(size_t)node * D2 + 0] =
          fmaxf(s0 * sc + b2l[0] + r0p[0] + r1p[0], 0.f);
      out[(size_t)node * D2 + 1] =
          fmaxf(s1 * sc + b2l[1] + r0p[1] + r1p[1], 0.f);
      out[(size_t)node * D2 + 2] =
          fmaxf(s2 * sc + b2l[2] + r0p[2] + r1p[2], 0.f);
      out[(size_t)node * D2 + 3] =
          fmaxf(s3 * sc + b2l[3] + r0p[3] + r1p[3], 0.f);
    } else {
      out[(size_t)node * D2 + 4] =
          fmaxf(s0 * sc + b2l[4] + r0p[4] + r1p[4], 0.f);
    }
  }
}

extern "C" void kernel_launch(void* const* d_in, const int* in_sizes, int n_in,
                              void* d_out, int out_size, void* d_ws,
                              size_t ws_size, hipStream_t stream) {
  const float* x   = (const float*)d_in[0];
  const int*   ei  = (const int*)d_in[1];
  const int*   src = ei;
  const int*   dst = ei + NE;
  const float* W1l = (const float*)d_in[2];
  const float* b1l = (const float*)d_in[3];
  const float* W1r = (const float*)d_in[4];
  const float* W2l = (const float*)d_in[5];
  const float* b2l = (const float*)d_in[6];
  const float* W2r = (const float*)d_in[7];
  float* out = (float*)d_out;

  // workspace layout: big aligned arrays first (16B-aligned offsets)
  unsigned short* ab  = (unsigned short*)d_ws;          // NN*256 bf16
  unsigned short* wb  = ab + (size_t)NN * 256;          // 256*256 bf16
  unsigned short* w2b = wb + 256 * 256;                 // 16*256 bf16
  float* tt   = (float*)(w2b + 16 * 256);               // NN*16 (t interleaved)
  float* rp   = tt + (size_t)NN * 16;                   // 2 * NN*8 (r partials)
  uint2* slab = (uint2*)(rp + (size_t)NN * 16);         // NBUK*CAP pairs
  int*   gcur = (int*)(slab + (size_t)NBUK * CAP);      // 256
  int*   esort = gcur + 256;                            // NE (16B aligned)
  int*   cur  = esort + NE;                             // NN+1 (+3 pad)
  float* inv  = (float*)(cur + NN + 4);                 // NN

  hipMemsetAsync(gcur, 0, 256 * sizeof(int), stream);

  k_prepA<<<CB + XB + WB + PB, 256, 0, stream>>>(x, ab, W1l, W1r, wb, W2l, W2r,
                                                 w2b, src, dst, gcur, slab);
  k_bucketBC<<<NBUK, 512, 0, stream>>>(slab, gcur, cur, inv, esort);
  k_agg1<<<(NN * 64 + 255) / 256, 256, 0, stream>>>(ab, esort, cur, inv);
  dim3 g1(2, (NN + 127) / 128);
  k_gemm1f<<<g1, 256, 0, stream>>>(ab, wb, w2b, b1l, tt, rp);
  k_layer2<<<(NN + 15) / 16, 256, 0, stream>>>(tt, rp, esort, cur, inv, b2l,
                                               out);
}